// Round 5
// baseline (133.537 us; speedup 1.0000x reference)
//
#include <hip/hip_runtime.h>
#include <hip/hip_bf16.h>
#include <hip/hip_cooperative_groups.h>

namespace cg = cooperative_groups;

// MLP_64450279244218: o[w][q] = relu(relu(relu((x[w]-y[q])@W1+b1)@W2+b2)@W3+b3)
// (x-y)@W1 = x@W1 - y@W1 -> projections computed once.
// Single cooperative kernel, 512 blocks x 256 thr (co-residency needs only
// 2 blocks/CU -- large margin vs R4's exact-capacity 1024 which failed):
//   phase 1: blocks 0..255 project rows 4b..4b+3 (fp32, 4-wave k-split 400,
//            LDS reduce) -> P[1024][64] (+b1 folded into x rows).
//   grid.sync() (cooperative groups; runtime-managed barrier, replay-safe)
//   phase 2: each block computes two 16x16 pair tiles (R3-validated tile code:
//            bf16 MFMA layer-2, fp32 shfl-reduced layer-3).
// Fallback: if hipLaunchCooperativeKernel errors, launch the same device code
// as two ordinary kernels (== R3 structure).

#define IN_DIM 1600
#define H1D 64
#define H2D 32
#define NROW 512
#define KCH 400   // k per wave in phase 1 (4 waves)

typedef short bf16x8 __attribute__((ext_vector_type(8)));
typedef float f32x4 __attribute__((ext_vector_type(4)));

struct SmemT {
  float sX[16][68];   // 272B row stride -> b128 conflict-free
  float sY[16][68];
  float sO[16][16];
};

static __device__ __forceinline__ short f2bf(float v) {
  __hip_bfloat16 h = __float2bfloat16(v);
  return *reinterpret_cast<short*>(&h);
}

// ---- phase 1 body: project rows 4*pb .. 4*pb+3 into P (pacc >= 1024 floats) ----
static __device__ __forceinline__ void produce4rows(
    int pb, int tid, const float* __restrict__ x, const float* __restrict__ y,
    const float* __restrict__ W1, const float* __restrict__ b1,
    float* __restrict__ P, float* pacc) {
  const int lane = tid & 63;
  const int w = __builtin_amdgcn_readfirstlane(tid >> 6);   // 0..3
  const int row0 = pb * 4;
  const float* __restrict__ base = (row0 < NROW) ? x : y;
  const int r0 = (row0 < NROW) ? row0 : row0 - NROW;
  const int k0 = w * KCH;
  const float* __restrict__ xr0 = base + (size_t)(r0 + 0) * IN_DIM + k0;
  const float* __restrict__ xr1 = base + (size_t)(r0 + 1) * IN_DIM + k0;
  const float* __restrict__ xr2 = base + (size_t)(r0 + 2) * IN_DIM + k0;
  const float* __restrict__ xr3 = base + (size_t)(r0 + 3) * IN_DIM + k0;
  const float* __restrict__ wp = W1 + (size_t)k0 * H1D + lane;

  float a0 = 0.f, a1 = 0.f, a2 = 0.f, a3 = 0.f;
#pragma unroll 16
  for (int i = 0; i < KCH; ++i) {
    const float wv = wp[(size_t)i * H1D];     // coalesced 256B/wave
    a0 = fmaf(xr0[i], wv, a0);                // wave-uniform -> s_load stream
    a1 = fmaf(xr1[i], wv, a1);
    a2 = fmaf(xr2[i], wv, a2);
    a3 = fmaf(xr3[i], wv, a3);
  }
  pacc[(w * 4 + 0) * 64 + lane] = a0;
  pacc[(w * 4 + 1) * 64 + lane] = a1;
  pacc[(w * 4 + 2) * 64 + lane] = a2;
  pacc[(w * 4 + 3) * 64 + lane] = a3;
  __syncthreads();
  {
    const int r = tid >> 6, h = tid & 63;
    float s = pacc[(0 + r) * 64 + h] + pacc[(4 + r) * 64 + h] +
              pacc[(8 + r) * 64 + h] + pacc[(12 + r) * 64 + h];
    if (row0 < NROW) s += b1[h];              // fold b1 into x side
    P[(size_t)(row0 + r) * H1D + h] = s;
  }
}

// ---- phase 2 body: one 16x16 pair tile (validated in R3) ----
static __device__ __forceinline__ void do_tile(
    int ip, int jp, int tid, const float* __restrict__ P,
    const bf16x8 bfr[2][2], float b2v0, float b2v1,
    float w3v0, float w3v1, float b3v,
    float* __restrict__ out, SmemT& sm) {
  const int wave = tid >> 6, lane = tid & 63;
  const int l15 = lane & 15, l4 = lane >> 4;
  const int wb = ip * 16, qb = jp * 16;

  {  // stage both 16x64 tiles (one float4 per thread each)
    const int r = tid >> 4, c = (tid & 15) * 4;
    const float4 vx = *reinterpret_cast<const float4*>(&P[(size_t)(wb + r) * H1D + c]);
    const float4 vy = *reinterpret_cast<const float4*>(&P[(size_t)(NROW + qb + r) * H1D + c]);
    *reinterpret_cast<float4*>(&sm.sX[r][c]) = vx;
    *reinterpret_cast<float4*>(&sm.sY[r][c]) = vy;
  }
  __syncthreads();

  f32x4 acc[4][2];
#pragma unroll
  for (int mt = 0; mt < 4; ++mt)
#pragma unroll
    for (int r = 0; r < 4; ++r) { acc[mt][0][r] = b2v0; acc[mt][1][r] = b2v1; }

  // A fragments: row = l15 (y idx), k = ks*32 + l4*8 + j ; value = relu(Px-Py)
#pragma unroll
  for (int ks = 0; ks < 2; ++ks) {
    const int kb = ks * 32 + l4 * 8;
    const float4 y0 = *reinterpret_cast<const float4*>(&sm.sY[l15][kb]);
    const float4 y1 = *reinterpret_cast<const float4*>(&sm.sY[l15][kb + 4]);
#pragma unroll
    for (int mt = 0; mt < 4; ++mt) {
      const int lw = wave * 4 + mt;
      const float4 x0 = *reinterpret_cast<const float4*>(&sm.sX[lw][kb]);
      const float4 x1 = *reinterpret_cast<const float4*>(&sm.sX[lw][kb + 4]);
      bf16x8 af; float v;
      v = x0.x - y0.x; af[0] = f2bf(v > 0.f ? v : 0.f);
      v = x0.y - y0.y; af[1] = f2bf(v > 0.f ? v : 0.f);
      v = x0.z - y0.z; af[2] = f2bf(v > 0.f ? v : 0.f);
      v = x0.w - y0.w; af[3] = f2bf(v > 0.f ? v : 0.f);
      v = x1.x - y1.x; af[4] = f2bf(v > 0.f ? v : 0.f);
      v = x1.y - y1.y; af[5] = f2bf(v > 0.f ? v : 0.f);
      v = x1.z - y1.z; af[6] = f2bf(v > 0.f ? v : 0.f);
      v = x1.w - y1.w; af[7] = f2bf(v > 0.f ? v : 0.f);
      acc[mt][0] = __builtin_amdgcn_mfma_f32_16x16x32_bf16(af, bfr[0][ks], acc[mt][0], 0, 0, 0);
      acc[mt][1] = __builtin_amdgcn_mfma_f32_16x16x32_bf16(af, bfr[1][ks], acc[mt][1], 0, 0, 0);
    }
  }

  // layer 3: o = relu(sum_n relu(h2[n]) * W3[n] + b3), reduce 16 n-lanes
#pragma unroll
  for (int mt = 0; mt < 4; ++mt) {
    float t[4];
#pragma unroll
    for (int r = 0; r < 4; ++r) {
      const float q0 = acc[mt][0][r] > 0.f ? acc[mt][0][r] : 0.f;
      const float q1 = acc[mt][1][r] > 0.f ? acc[mt][1][r] : 0.f;
      t[r] = fmaf(q0, w3v0, q1 * w3v1);
    }
#pragma unroll
    for (int off = 1; off < 16; off <<= 1) {
#pragma unroll
      for (int r = 0; r < 4; ++r) t[r] += __shfl_xor(t[r], off, 64);
    }
    if (l15 == 0) {
#pragma unroll
      for (int r = 0; r < 4; ++r) {
        const float o = t[r] + b3v;
        sm.sO[wave * 4 + mt][l4 * 4 + r] = o > 0.f ? o : 0.f;   // [lw][lq]
      }
    }
  }
  __syncthreads();
  out[(size_t)(wb + (tid >> 4)) * NROW + qb + (tid & 15)] = sm.sO[tid >> 4][tid & 15];
}

// ---- B-fragment (W2) prep, per block from global (8KB, L1/L2-hot) ----
static __device__ __forceinline__ void load_bfr(
    int lane, const float* __restrict__ W2, bf16x8 bfr[2][2]) {
  const int l15 = lane & 15, l4 = lane >> 4;
#pragma unroll
  for (int nt = 0; nt < 2; ++nt)
#pragma unroll
    for (int ks = 0; ks < 2; ++ks)
#pragma unroll
      for (int j = 0; j < 8; ++j)
        bfr[nt][ks][j] = f2bf(W2[(ks * 32 + l4 * 8 + j) * H2D + nt * 16 + l15]);
}

// ---------------- fused cooperative kernel ----------------
__global__ __launch_bounds__(256) void fused_kernel(
    const float* __restrict__ x, const float* __restrict__ y,
    const float* __restrict__ W1, const float* __restrict__ b1,
    const float* __restrict__ W2, const float* __restrict__ b2,
    const float* __restrict__ W3, const float* __restrict__ b3,
    float* __restrict__ P, float* __restrict__ out) {
  __shared__ SmemT sm;
  const int tid = threadIdx.x;
  const int lane = tid & 63;
  const int l15 = lane & 15;

  bf16x8 bfr[2][2];
  load_bfr(lane, W2, bfr);
  const float b2v0 = b2[l15], b2v1 = b2[16 + l15];
  const float w3v0 = W3[l15], w3v1 = W3[16 + l15];
  const float b3v = b3[0];

  if (blockIdx.x < 256)
    produce4rows((int)blockIdx.x, tid, x, y, W1, b1, P, &sm.sX[0][0]);
  __threadfence();          // make P visible device-wide (cross-XCD)
  cg::this_grid().sync();   // runtime-managed grid barrier

  const int t0 = (int)blockIdx.x * 2;
  do_tile(t0 >> 5, t0 & 31, tid, P, bfr, b2v0, b2v1, w3v0, w3v1, b3v, out, sm);
  do_tile((t0 + 1) >> 5, (t0 + 1) & 31, tid, P, bfr, b2v0, b2v1, w3v0, w3v1, b3v, out, sm);
}

// ---------------- fallback: same code as two ordinary kernels ----------------
__global__ __launch_bounds__(256) void phase1_kernel(
    const float* __restrict__ x, const float* __restrict__ y,
    const float* __restrict__ W1, const float* __restrict__ b1,
    float* __restrict__ P) {
  __shared__ float pacc[1024];
  produce4rows((int)blockIdx.x, threadIdx.x, x, y, W1, b1, P, pacc);
}

__global__ __launch_bounds__(256) void phase2_kernel(
    const float* __restrict__ P, const float* __restrict__ W2,
    const float* __restrict__ b2, const float* __restrict__ W3,
    const float* __restrict__ b3, float* __restrict__ out) {
  __shared__ SmemT sm;
  const int tid = threadIdx.x;
  const int lane = tid & 63;
  const int l15 = lane & 15;
  bf16x8 bfr[2][2];
  load_bfr(lane, W2, bfr);
  const float b2v0 = b2[l15], b2v1 = b2[16 + l15];
  const float w3v0 = W3[l15], w3v1 = W3[16 + l15];
  const float b3v = b3[0];
  const int t0 = (int)blockIdx.x * 2;
  do_tile(t0 >> 5, t0 & 31, tid, P, bfr, b2v0, b2v1, w3v0, w3v1, b3v, out, sm);
  do_tile((t0 + 1) >> 5, (t0 + 1) & 31, tid, P, bfr, b2v0, b2v1, w3v0, w3v1, b3v, out, sm);
}

extern "C" void kernel_launch(void* const* d_in, const int* in_sizes, int n_in,
                              void* d_out, int out_size, void* d_ws, size_t ws_size,
                              hipStream_t stream) {
  const float* x  = (const float*)d_in[0];
  const float* y  = (const float*)d_in[1];
  const float* W1 = (const float*)d_in[2];
  const float* b1 = (const float*)d_in[3];
  const float* W2 = (const float*)d_in[4];
  const float* b2 = (const float*)d_in[5];
  const float* W3 = (const float*)d_in[6];
  const float* b3 = (const float*)d_in[7];
  float* out = (float*)d_out;
  float* P = (float*)d_ws;   // 1024*64*4 = 256 KB

  void* args[] = {(void*)&x, (void*)&y, (void*)&W1, (void*)&b1,
                  (void*)&W2, (void*)&b2, (void*)&W3, (void*)&b3,
                  (void*)&P, (void*)&out};
  hipError_t e = hipLaunchCooperativeKernel(
      (const void*)fused_kernel, dim3(512), dim3(256), args, 0, stream);
  if (e != hipSuccess) {
    // fallback: plain 2-kernel path (identical math)
    phase1_kernel<<<256, 256, 0, stream>>>(x, y, W1, b1, P);
    phase2_kernel<<<512, 256, 0, stream>>>(P, W2, b2, W3, b3, out);
  }
}

// Round 6
// 66.070 us; speedup vs baseline: 2.0211x; 2.0211x over previous
//
#include <hip/hip_runtime.h>
#include <hip/hip_bf16.h>

// MLP_64450279244218: o[w][q] = relu(relu(relu((x[w]-y[q])@W1+b1)@W2+b2)@W3+b3)
// (x-y)@W1 = x@W1 - y@W1 -> projections computed once.
// SINGLE plain kernel (no cooperative launch), 1024 blocks x 256 thr:
//   producers (blocks 0..255): rows 4b..4b+3, 4-wave k-split 400, x/y rows read
//     via pointer-laundered uniform global_load_dwordx4 (vmcnt-pipelined, not
//     s_load), LDS reduce, write P, publish per-16-row-panel flag
//     (release atomic, agent scope -> buffer_wbl2).
//   consumers (all 1024 blocks, 1 tile each): relaxed-poll 2 panel flags +
//     one acquire fence (buffer_inv), then R3-validated 16x16 MFMA pair tile.
// Deadlock-free without coop: >=2 blocks/CU resident => blocks 0..511 all
// resident => every producer runs; consumers only wait on producers.

#define IN_DIM 1600
#define H1D 64
#define H2D 32
#define NROW 512
#define KCH 400   // k per wave in producer (4 waves)

typedef short bf16x8 __attribute__((ext_vector_type(8)));
typedef float f32x4 __attribute__((ext_vector_type(4)));

struct SmemT {
  float sX[16][68];   // 272B row stride -> b128 conflict-free
  float sY[16][68];
  float sO[16][16];
};

static __device__ __forceinline__ short f2bf(float v) {
  __hip_bfloat16 h = __float2bfloat16(v);
  return *reinterpret_cast<short*>(&h);
}

// ---- B-fragment (W2) prep, per block from global (8KB, L1/L2-hot) ----
static __device__ __forceinline__ void load_bfr(
    int lane, const float* __restrict__ W2, bf16x8 bfr[2][2]) {
  const int l15 = lane & 15, l4 = lane >> 4;
#pragma unroll
  for (int nt = 0; nt < 2; ++nt)
#pragma unroll
    for (int ks = 0; ks < 2; ++ks)
#pragma unroll
      for (int j = 0; j < 8; ++j)
        bfr[nt][ks][j] = f2bf(W2[(ks * 32 + l4 * 8 + j) * H2D + nt * 16 + l15]);
}

// ---- producer: project rows 4*pb..4*pb+3 into P (pacc >= 1024 floats) ----
static __device__ __forceinline__ void produce4rows(
    int pb, int tid, const float* __restrict__ x, const float* __restrict__ y,
    const float* __restrict__ W1, const float* __restrict__ b1,
    float* __restrict__ P, float* pacc) {
  const int lane = tid & 63;
  const int w = __builtin_amdgcn_readfirstlane(tid >> 6);   // 0..3
  const int row0 = pb * 4;
  const float* __restrict__ base = (row0 < NROW) ? x : y;
  const int r0 = (row0 < NROW) ? row0 : row0 - NROW;
  const int k0 = w * KCH;

  // Launder row pointers into VGPRs: forces global_load (vector path, deep
  // vmcnt pipelining + HW broadcast of uniform address) instead of s_load
  // chains that serialized on SGPR pressure.
  const float* xr0 = base + (size_t)(r0 + 0) * IN_DIM + k0;
  const float* xr1 = base + (size_t)(r0 + 1) * IN_DIM + k0;
  const float* xr2 = base + (size_t)(r0 + 2) * IN_DIM + k0;
  const float* xr3 = base + (size_t)(r0 + 3) * IN_DIM + k0;
  asm volatile("" : "+v"(xr0), "+v"(xr1), "+v"(xr2), "+v"(xr3));
  const float* __restrict__ wp = W1 + (size_t)k0 * H1D + lane;

  float a0 = 0.f, a1 = 0.f, a2 = 0.f, a3 = 0.f;
#pragma unroll 4
  for (int c = 0; c < KCH / 4; ++c) {           // chunks of 4 k
    const int k = c * 4;
    const float4 xv0 = *reinterpret_cast<const float4*>(xr0 + k);
    const float4 xv1 = *reinterpret_cast<const float4*>(xr1 + k);
    const float4 xv2 = *reinterpret_cast<const float4*>(xr2 + k);
    const float4 xv3 = *reinterpret_cast<const float4*>(xr3 + k);
    const float w0 = wp[(size_t)(k + 0) * H1D];  // coalesced 256B/wave
    const float w1 = wp[(size_t)(k + 1) * H1D];
    const float w2 = wp[(size_t)(k + 2) * H1D];
    const float w3 = wp[(size_t)(k + 3) * H1D];
    a0 = fmaf(xv0.x, w0, fmaf(xv0.y, w1, fmaf(xv0.z, w2, fmaf(xv0.w, w3, a0))));
    a1 = fmaf(xv1.x, w0, fmaf(xv1.y, w1, fmaf(xv1.z, w2, fmaf(xv1.w, w3, a1))));
    a2 = fmaf(xv2.x, w0, fmaf(xv2.y, w1, fmaf(xv2.z, w2, fmaf(xv2.w, w3, a2))));
    a3 = fmaf(xv3.x, w0, fmaf(xv3.y, w1, fmaf(xv3.z, w2, fmaf(xv3.w, w3, a3))));
  }
  pacc[(w * 4 + 0) * 64 + lane] = a0;
  pacc[(w * 4 + 1) * 64 + lane] = a1;
  pacc[(w * 4 + 2) * 64 + lane] = a2;
  pacc[(w * 4 + 3) * 64 + lane] = a3;
  __syncthreads();
  {
    const int r = tid >> 6, h = tid & 63;
    float s = pacc[(0 + r) * 64 + h] + pacc[(4 + r) * 64 + h] +
              pacc[(8 + r) * 64 + h] + pacc[(12 + r) * 64 + h];
    if (row0 < NROW) s += b1[h];              // fold b1 into x side
    P[(size_t)(row0 + r) * H1D + h] = s;
  }
}

// ---- consumer: one 16x16 pair tile (validated R3/R5) ----
static __device__ __forceinline__ void do_tile(
    int ip, int jp, int tid, const float* __restrict__ P,
    const bf16x8 bfr[2][2], float b2v0, float b2v1,
    float w3v0, float w3v1, float b3v,
    float* __restrict__ out, SmemT& sm) {
  const int wave = tid >> 6, lane = tid & 63;
  const int l15 = lane & 15, l4 = lane >> 4;
  const int wb = ip * 16, qb = jp * 16;

  {  // stage both 16x64 tiles (one float4 per thread each)
    const int r = tid >> 4, c = (tid & 15) * 4;
    const float4 vx = *reinterpret_cast<const float4*>(&P[(size_t)(wb + r) * H1D + c]);
    const float4 vy = *reinterpret_cast<const float4*>(&P[(size_t)(NROW + qb + r) * H1D + c]);
    *reinterpret_cast<float4*>(&sm.sX[r][c]) = vx;
    *reinterpret_cast<float4*>(&sm.sY[r][c]) = vy;
  }
  __syncthreads();

  f32x4 acc[4][2];
#pragma unroll
  for (int mt = 0; mt < 4; ++mt)
#pragma unroll
    for (int r = 0; r < 4; ++r) { acc[mt][0][r] = b2v0; acc[mt][1][r] = b2v1; }

  // A fragments: row = l15 (y idx), k = ks*32 + l4*8 + j ; value = relu(Px-Py)
#pragma unroll
  for (int ks = 0; ks < 2; ++ks) {
    const int kb = ks * 32 + l4 * 8;
    const float4 y0 = *reinterpret_cast<const float4*>(&sm.sY[l15][kb]);
    const float4 y1 = *reinterpret_cast<const float4*>(&sm.sY[l15][kb + 4]);
#pragma unroll
    for (int mt = 0; mt < 4; ++mt) {
      const int lw = wave * 4 + mt;
      const float4 x0 = *reinterpret_cast<const float4*>(&sm.sX[lw][kb]);
      const float4 x1 = *reinterpret_cast<const float4*>(&sm.sX[lw][kb + 4]);
      bf16x8 af; float v;
      v = x0.x - y0.x; af[0] = f2bf(v > 0.f ? v : 0.f);
      v = x0.y - y0.y; af[1] = f2bf(v > 0.f ? v : 0.f);
      v = x0.z - y0.z; af[2] = f2bf(v > 0.f ? v : 0.f);
      v = x0.w - y0.w; af[3] = f2bf(v > 0.f ? v : 0.f);
      v = x1.x - y1.x; af[4] = f2bf(v > 0.f ? v : 0.f);
      v = x1.y - y1.y; af[5] = f2bf(v > 0.f ? v : 0.f);
      v = x1.z - y1.z; af[6] = f2bf(v > 0.f ? v : 0.f);
      v = x1.w - y1.w; af[7] = f2bf(v > 0.f ? v : 0.f);
      acc[mt][0] = __builtin_amdgcn_mfma_f32_16x16x32_bf16(af, bfr[0][ks], acc[mt][0], 0, 0, 0);
      acc[mt][1] = __builtin_amdgcn_mfma_f32_16x16x32_bf16(af, bfr[1][ks], acc[mt][1], 0, 0, 0);
    }
  }

  // layer 3: o = relu(sum_n relu(h2[n]) * W3[n] + b3), reduce 16 n-lanes
#pragma unroll
  for (int mt = 0; mt < 4; ++mt) {
    float t[4];
#pragma unroll
    for (int r = 0; r < 4; ++r) {
      const float q0 = acc[mt][0][r] > 0.f ? acc[mt][0][r] : 0.f;
      const float q1 = acc[mt][1][r] > 0.f ? acc[mt][1][r] : 0.f;
      t[r] = fmaf(q0, w3v0, q1 * w3v1);
    }
#pragma unroll
    for (int off = 1; off < 16; off <<= 1) {
#pragma unroll
      for (int r = 0; r < 4; ++r) t[r] += __shfl_xor(t[r], off, 64);
    }
    if (l15 == 0) {
#pragma unroll
      for (int r = 0; r < 4; ++r) {
        const float o = t[r] + b3v;
        sm.sO[wave * 4 + mt][l4 * 4 + r] = o > 0.f ? o : 0.f;   // [lw][lq]
      }
    }
  }
  __syncthreads();
  out[(size_t)(wb + (tid >> 4)) * NROW + qb + (tid & 15)] = sm.sO[tid >> 4][tid & 15];
}

// ---------------- fused kernel (plain launch) ----------------
__global__ __launch_bounds__(256) void fused_kernel(
    const float* __restrict__ x, const float* __restrict__ y,
    const float* __restrict__ W1, const float* __restrict__ b1,
    const float* __restrict__ W2, const float* __restrict__ b2,
    const float* __restrict__ W3, const float* __restrict__ b3,
    float* __restrict__ P, unsigned int* __restrict__ flags,
    float* __restrict__ out) {
  __shared__ SmemT sm;
  const int tid = threadIdx.x;
  const int lane = tid & 63;
  const int l15 = lane & 15;
  const int bid = blockIdx.x;

  // consumer constants loaded BEFORE the spin (overlaps producer latency;
  // values live in VGPRs, immune to the acquire invalidate)
  bf16x8 bfr[2][2];
  load_bfr(lane, W2, bfr);
  const float b2v0 = b2[l15], b2v1 = b2[16 + l15];
  const float w3v0 = W3[l15], w3v1 = W3[16 + l15];
  const float b3v = b3[0];

  if (bid < 256) {
    produce4rows(bid, tid, x, y, W1, b1, P, &sm.sX[0][0]);
    __syncthreads();
    if (tid == 0)
      __hip_atomic_fetch_add(&flags[bid >> 2], 1u,
                             __ATOMIC_RELEASE, __HIP_MEMORY_SCOPE_AGENT);
  }

  // ---- consumer: 1 tile per block ----
  const int ip = bid >> 5, jp = bid & 31;
  if (tid == 0) {
    int guard = 0;
    while (__hip_atomic_load(&flags[ip], __ATOMIC_RELAXED,
                             __HIP_MEMORY_SCOPE_AGENT) < 4u &&
           ++guard < (1 << 22))
      __builtin_amdgcn_s_sleep(2);
    while (__hip_atomic_load(&flags[32 + jp], __ATOMIC_RELAXED,
                             __HIP_MEMORY_SCOPE_AGENT) < 4u &&
           ++guard < (1 << 22))
      __builtin_amdgcn_s_sleep(2);
    __threadfence();   // acquire: buffer_inv -> subsequent P reads see LLC
  }
  __syncthreads();     // also orders pacc/sm reuse

  do_tile(ip, jp, tid, P, bfr, b2v0, b2v1, w3v0, w3v1, b3v, out, sm);
}

extern "C" void kernel_launch(void* const* d_in, const int* in_sizes, int n_in,
                              void* d_out, int out_size, void* d_ws, size_t ws_size,
                              hipStream_t stream) {
  const float* x  = (const float*)d_in[0];
  const float* y  = (const float*)d_in[1];
  const float* W1 = (const float*)d_in[2];
  const float* b1 = (const float*)d_in[3];
  const float* W2 = (const float*)d_in[4];
  const float* b2 = (const float*)d_in[5];
  const float* W3 = (const float*)d_in[6];
  const float* b3 = (const float*)d_in[7];
  float* out = (float*)d_out;

  char* ws = (char*)d_ws;
  float* P = (float*)ws;                                        // 256 KB
  unsigned int* flags = (unsigned int*)(ws + 1024 * H1D * 4);   // 64 counters

  hipMemsetAsync(flags, 0, 64 * sizeof(unsigned int), stream);
  fused_kernel<<<1024, 256, 0, stream>>>(x, y, W1, b1, W2, b2, W3, b3,
                                         P, flags, out);
}

// Round 7
// 26.328 us; speedup vs baseline: 5.0720x; 2.5095x over previous
//
#include <hip/hip_runtime.h>
#include <hip/hip_bf16.h>

// MLP_64450279244218: o[w][q] = relu(relu(relu((x[w]-y[q])@W1+b1)@W2+b2)@W3+b3)
// (x-y)@W1 = x@W1 - y@W1 -> projections computed once.
// K0 prep: x,y -> bf16 hi/lo split XH/XL[1024][1600]; W1 -> transposed bf16
//          hi/lo WTH/WTL[64][1600].  (all-coalesced except tiny W1 transpose)
// K1 proj: PTp[q][64][1024] = (W1^T . X^T) via mfma_f32_16x16x32_bf16 with
//          3-term precision split Wh*Xh + Wl*Xh + Wh*Xl (error ~2^-16 rel ->
//          fp32-grade). Per wave: one 16-h m-tile x 16 rows x k-quarter.
//          Every fragment load = contiguous 16B/lane. No LDS, no sync.
// K2 pair: 16x16 pair tile (R3-validated): stage sX/sY by summing the 4
//          k-quarter partials (+b1 on x side), h1 -> bf16 A-frags, layer-2
//          MFMA, layer-3 fp32 shfl-reduce.

#define IN_DIM 1600
#define H1D 64
#define H2D 32
#define NROW 512
#define NTOT 1024
#define KC_TOT 50   // 1600/32 k-chunks
#define KQ 4        // proj k-split

typedef short bf16x8 __attribute__((ext_vector_type(8)));
typedef float f32x4 __attribute__((ext_vector_type(4)));

static __device__ __forceinline__ unsigned short f2bf_u(float v) {
  __hip_bfloat16 h = __float2bfloat16(v);
  return *reinterpret_cast<unsigned short*>(&h);
}
static __device__ __forceinline__ float bf2f(unsigned short u) {
  __hip_bfloat16 h = *reinterpret_cast<__hip_bfloat16*>(&u);
  return __bfloat162float(h);
}

// ---------------- K0: precision-split + transpose prep ----------------
__global__ __launch_bounds__(256) void prep_kernel(
    const float* __restrict__ x, const float* __restrict__ y,
    const float* __restrict__ W1,
    unsigned short* __restrict__ XH, unsigned short* __restrict__ XL,
    unsigned short* __restrict__ WTH, unsigned short* __restrict__ WTL) {
  const int t = blockIdx.x * 256 + threadIdx.x;
  if (t < NTOT * 400) {                      // x/y: 409600 float4 groups
    const int row = t / 400;
    const int k4 = (t % 400) * 4;
    const float* src = (row < NROW) ? (x + (size_t)row * IN_DIM + k4)
                                    : (y + (size_t)(row - NROW) * IN_DIM + k4);
    const float4 v = *reinterpret_cast<const float4*>(src);
    ushort4 hi, lo;
    hi.x = f2bf_u(v.x); lo.x = f2bf_u(v.x - bf2f(hi.x));
    hi.y = f2bf_u(v.y); lo.y = f2bf_u(v.y - bf2f(hi.y));
    hi.z = f2bf_u(v.z); lo.z = f2bf_u(v.z - bf2f(hi.z));
    hi.w = f2bf_u(v.w); lo.w = f2bf_u(v.w - bf2f(hi.w));
    *reinterpret_cast<ushort4*>(&XH[(size_t)row * IN_DIM + k4]) = hi;
    *reinterpret_cast<ushort4*>(&XL[(size_t)row * IN_DIM + k4]) = lo;
  } else {                                   // W1 transpose: 51200 x 2 elems
    const int j = t - NTOT * 400;
    if (j < H1D * IN_DIM / 2) {
      const int o = j * 2;                   // linear index into [64][1600]
      const int h = o / IN_DIM, k = o % IN_DIM;
      const float a = W1[(size_t)k * H1D + h];
      const float b = W1[(size_t)(k + 1) * H1D + h];
      ushort2 hh, ll;
      hh.x = f2bf_u(a); ll.x = f2bf_u(a - bf2f(hh.x));
      hh.y = f2bf_u(b); ll.y = f2bf_u(b - bf2f(hh.y));
      *reinterpret_cast<ushort2*>(&WTH[o]) = hh;
      *reinterpret_cast<ushort2*>(&WTL[o]) = ll;
    }
  }
}

// ---------------- K1: projection via MFMA ----------------
// PTp[q][h][row] partial over k-quarter q. Wave = m-tile (16 h); block covers
// 16 rows (nc) x k-quarter (q). A = W1T (row=l15 -> h), B = X (col=l15 -> row).
__global__ __launch_bounds__(256) void proj_kernel(
    const unsigned short* __restrict__ XH, const unsigned short* __restrict__ XL,
    const unsigned short* __restrict__ WTH, const unsigned short* __restrict__ WTL,
    float* __restrict__ PTp) {
  const int tid = threadIdx.x, lane = tid & 63;
  const int mt = tid >> 6;                       // wave = m-tile 0..3
  const int l15 = lane & 15, l4 = lane >> 4;
  const int nc = (int)blockIdx.x >> 2;           // row-chunk 0..63 (16 rows)
  const int q = (int)blockIdx.x & 3;             // k-quarter
  const int kc0 = (q * KC_TOT) >> 2, kc1 = ((q + 1) * KC_TOT) >> 2;

  const size_t wrow = (size_t)(mt * 16 + l15) * IN_DIM;   // A-frag row (h)
  const size_t xrow = (size_t)(nc * 16 + l15) * IN_DIM;   // B-frag col (x-row)

  f32x4 aA = {0.f, 0.f, 0.f, 0.f};
  f32x4 aB = {0.f, 0.f, 0.f, 0.f};
  f32x4 aC = {0.f, 0.f, 0.f, 0.f};
  for (int kc = kc0; kc < kc1; ++kc) {
    const int ko = kc * 32 + l4 * 8;             // per-lane k base (16B chunk)
    const bf16x8 wh = *reinterpret_cast<const bf16x8*>(&WTH[wrow + ko]);
    const bf16x8 wl = *reinterpret_cast<const bf16x8*>(&WTL[wrow + ko]);
    const bf16x8 xh = *reinterpret_cast<const bf16x8*>(&XH[xrow + ko]);
    const bf16x8 xl = *reinterpret_cast<const bf16x8*>(&XL[xrow + ko]);
    aA = __builtin_amdgcn_mfma_f32_16x16x32_bf16(wh, xh, aA, 0, 0, 0);
    aB = __builtin_amdgcn_mfma_f32_16x16x32_bf16(wl, xh, aB, 0, 0, 0);
    aC = __builtin_amdgcn_mfma_f32_16x16x32_bf16(wh, xl, aC, 0, 0, 0);
  }
#pragma unroll
  for (int r = 0; r < 4; ++r) {                  // C: row(h)=l4*4+r, col=l15
    const int h = mt * 16 + l4 * 4 + r;
    PTp[((size_t)q * H1D + h) * NTOT + nc * 16 + l15] = aA[r] + aB[r] + aC[r];
  }
}

// ---------------- K2: pair tiles via MFMA (R3-validated body) ----------------
__global__ __launch_bounds__(256) void pair_kernel(
    const float* __restrict__ PTp, const float* __restrict__ b1,
    const float* __restrict__ W2, const float* __restrict__ b2,
    const float* __restrict__ W3, const float* __restrict__ b3,
    float* __restrict__ out) {
  __shared__ float sX[16][68];   // 272B row stride -> b128 conflict-free
  __shared__ float sY[16][68];
  __shared__ float sO[16][16];

  const int tid = threadIdx.x;
  const int wave = tid >> 6, lane = tid & 63;
  const int l15 = lane & 15, l4 = lane >> 4;
  const int wb = blockIdx.x * 16, qb = blockIdx.y * 16;

  {  // stage: sX[r][h] = sum_q PTp[q][h][wb+r] + b1[h]; sY from y cols, no b1
    const int h = tid >> 2, r0 = (tid & 3) << 2;
    f32x4 sx = {0.f, 0.f, 0.f, 0.f}, sy = {0.f, 0.f, 0.f, 0.f};
#pragma unroll
    for (int q = 0; q < KQ; ++q) {
      sx += *reinterpret_cast<const f32x4*>(&PTp[((size_t)q * H1D + h) * NTOT + wb + r0]);
      sy += *reinterpret_cast<const f32x4*>(&PTp[((size_t)q * H1D + h) * NTOT + NROW + qb + r0]);
    }
    const float b1h = b1[h];
#pragma unroll
    for (int i = 0; i < 4; ++i) {   // 2-way bank aliasing only (free)
      sX[r0 + i][h] = sx[i] + b1h;
      sY[r0 + i][h] = sy[i];
    }
  }

  // B fragments (W2) direct from global (8KB, L1/L2-hot)
  bf16x8 bfr[2][2];
#pragma unroll
  for (int nt = 0; nt < 2; ++nt)
#pragma unroll
    for (int ks = 0; ks < 2; ++ks)
#pragma unroll
      for (int j = 0; j < 8; ++j)
        bfr[nt][ks][j] = (short)f2bf_u(W2[(ks * 32 + l4 * 8 + j) * H2D + nt * 16 + l15]);
  const float b2v0 = b2[l15], b2v1 = b2[16 + l15];
  const float w3v0 = W3[l15], w3v1 = W3[16 + l15];
  const float b3v = b3[0];

  f32x4 acc[4][2];
#pragma unroll
  for (int mt = 0; mt < 4; ++mt)
#pragma unroll
    for (int r = 0; r < 4; ++r) { acc[mt][0][r] = b2v0; acc[mt][1][r] = b2v1; }

  __syncthreads();

  // A fragments: row = l15 (y idx), k = ks*32 + l4*8 + j ; value = relu(Px-Py)
#pragma unroll
  for (int ks = 0; ks < 2; ++ks) {
    const int kb = ks * 32 + l4 * 8;
    const float4 y0 = *reinterpret_cast<const float4*>(&sY[l15][kb]);
    const float4 y1 = *reinterpret_cast<const float4*>(&sY[l15][kb + 4]);
#pragma unroll
    for (int mt = 0; mt < 4; ++mt) {
      const int lw = wave * 4 + mt;
      const float4 x0 = *reinterpret_cast<const float4*>(&sX[lw][kb]);
      const float4 x1 = *reinterpret_cast<const float4*>(&sX[lw][kb + 4]);
      bf16x8 af; float v;
      v = x0.x - y0.x; af[0] = (short)f2bf_u(v > 0.f ? v : 0.f);
      v = x0.y - y0.y; af[1] = (short)f2bf_u(v > 0.f ? v : 0.f);
      v = x0.z - y0.z; af[2] = (short)f2bf_u(v > 0.f ? v : 0.f);
      v = x0.w - y0.w; af[3] = (short)f2bf_u(v > 0.f ? v : 0.f);
      v = x1.x - y1.x; af[4] = (short)f2bf_u(v > 0.f ? v : 0.f);
      v = x1.y - y1.y; af[5] = (short)f2bf_u(v > 0.f ? v : 0.f);
      v = x1.z - y1.z; af[6] = (short)f2bf_u(v > 0.f ? v : 0.f);
      v = x1.w - y1.w; af[7] = (short)f2bf_u(v > 0.f ? v : 0.f);
      acc[mt][0] = __builtin_amdgcn_mfma_f32_16x16x32_bf16(af, bfr[0][ks], acc[mt][0], 0, 0, 0);
      acc[mt][1] = __builtin_amdgcn_mfma_f32_16x16x32_bf16(af, bfr[1][ks], acc[mt][1], 0, 0, 0);
    }
  }

  // layer 3: o = relu(sum_n relu(h2[n]) * W3[n] + b3), reduce 16 n-lanes
#pragma unroll
  for (int mt = 0; mt < 4; ++mt) {
    float t[4];
#pragma unroll
    for (int r = 0; r < 4; ++r) {
      const float q0 = acc[mt][0][r] > 0.f ? acc[mt][0][r] : 0.f;
      const float q1 = acc[mt][1][r] > 0.f ? acc[mt][1][r] : 0.f;
      t[r] = fmaf(q0, w3v0, q1 * w3v1);
    }
#pragma unroll
    for (int off = 1; off < 16; off <<= 1) {
#pragma unroll
      for (int r = 0; r < 4; ++r) t[r] += __shfl_xor(t[r], off, 64);
    }
    if (l15 == 0) {
#pragma unroll
      for (int r = 0; r < 4; ++r) {
        const float o = t[r] + b3v;
        sO[wave * 4 + mt][l4 * 4 + r] = o > 0.f ? o : 0.f;   // [lw][lq]
      }
    }
  }
  __syncthreads();
  out[(size_t)(wb + (tid >> 4)) * NROW + qb + (tid & 15)] = sO[tid >> 4][tid & 15];
}

extern "C" void kernel_launch(void* const* d_in, const int* in_sizes, int n_in,
                              void* d_out, int out_size, void* d_ws, size_t ws_size,
                              hipStream_t stream) {
  const float* x  = (const float*)d_in[0];
  const float* y  = (const float*)d_in[1];
  const float* W1 = (const float*)d_in[2];
  const float* b1 = (const float*)d_in[3];
  const float* W2 = (const float*)d_in[4];
  const float* b2 = (const float*)d_in[5];
  const float* W3 = (const float*)d_in[6];
  const float* b3 = (const float*)d_in[7];
  float* out = (float*)d_out;

  char* ws = (char*)d_ws;
  float* PTp = (float*)ws;                                    // 4*64*1024*4 = 1 MB
  unsigned short* XH  = (unsigned short*)(ws + (1u << 20));               // 3.2 MB
  unsigned short* XL  = (unsigned short*)(ws + (1u << 20) + 3276800u);    // 3.2 MB
  unsigned short* WTH = (unsigned short*)(ws + (1u << 20) + 2 * 3276800u);        // 200 KB
  unsigned short* WTL = (unsigned short*)(ws + (1u << 20) + 2 * 3276800u + 204800u);

  prep_kernel<<<1800, 256, 0, stream>>>(x, y, W1, XH, XL, WTH, WTL);
  proj_kernel<<<256, 256, 0, stream>>>(XH, XL, WTH, WTL, PTp);
  pair_kernel<<<dim3(32, 32), 256, 0, stream>>>(PTp, b1, W2, b2, W3, b3, out);
}

// Round 9
// 20.818 us; speedup vs baseline: 6.4145x; 1.2647x over previous
//
#include <hip/hip_runtime.h>
#include <hip/hip_bf16.h>

// MLP_64450279244218: o[w][q] = relu(relu(relu((x[w]-y[q])@W1+b1)@W2+b2)@W3+b3)
// (x-y)@W1 = x@W1 - y@W1 -> projections computed once.
// TWO nodes (inter-node gap ~5us measured -> node count is precious):
// K1 proj: PTp[8][64][1024] = (W1^T . X^T) partials via mfma_f32_16x16x32_bf16,
//          bf16 hi/lo 3-term split (Wh*Xh + Wl*Xh + Wh*Xl) done IN-KERNEL from
//          raw fp32 x/y/W1 (prep kernel + bf16 round-trip eliminated).
//          Block = (row-chunk nc, k-eighth q); wave = m-tile (16 h).
// K2 pair: 16x16 pair tile (validated R3/R7): stage sX/sY summing 8 partials
//          (+b1 on x side), h1 -> bf16 A-frags, layer-2 MFMA, layer-3 fp32
//          shfl-reduce over 16 n-lanes.

#define IN_DIM 1600
#define H1D 64
#define H2D 32
#define NROW 512
#define NTOT 1024
#define KC_TOT 50   // 1600/32 k-chunks
#define KQ 8        // proj k-split (partials)

typedef short bf16x8 __attribute__((ext_vector_type(8)));
typedef float f32x4 __attribute__((ext_vector_type(4)));

static __device__ __forceinline__ unsigned short f2bf_u(float v) {
  __hip_bfloat16 h = __float2bfloat16(v);
  return *reinterpret_cast<unsigned short*>(&h);
}
static __device__ __forceinline__ float bf2f(unsigned short u) {
  __hip_bfloat16 h = *reinterpret_cast<__hip_bfloat16*>(&u);
  return __bfloat162float(h);
}
// split v into bf16 hi + lo (residual), returned by value (vector elements
// cannot bind to non-const references)
struct BfPair { short hi, lo; };
static __device__ __forceinline__ BfPair splitbf(float v) {
  BfPair p;
  const unsigned short h = f2bf_u(v);
  p.hi = (short)h;
  p.lo = (short)f2bf_u(v - bf2f(h));
  return p;
}

// ---------------- K1: projection via MFMA, fused bf16 split ----------------
// A = W1T (frag row = h), B = X (frag col = x-row). C row(h)=l4*4+r, col=l15.
__global__ __launch_bounds__(256) void proj_kernel(
    const float* __restrict__ x, const float* __restrict__ y,
    const float* __restrict__ W1, float* __restrict__ PTp) {
  const int tid = threadIdx.x, lane = tid & 63;
  const int mt = tid >> 6;                       // wave = m-tile 0..3
  const int l15 = lane & 15, l4 = lane >> 4;
  const int nc = (int)blockIdx.x >> 3;           // row-chunk 0..63 (16 rows)
  const int q = (int)blockIdx.x & 7;             // k-eighth
  const int kc0 = (q * KC_TOT) >> 3, kc1 = ((q + 1) * KC_TOT) >> 3;

  const int hrow = mt * 16 + l15;                // A-frag row (h)
  const int xrow = nc * 16 + l15;                // B-frag col (x-row)
  const float* __restrict__ xs =
      (xrow < NROW) ? (x + (size_t)xrow * IN_DIM)
                    : (y + (size_t)(xrow - NROW) * IN_DIM);

  f32x4 aA = {0.f, 0.f, 0.f, 0.f};
  f32x4 aB = {0.f, 0.f, 0.f, 0.f};
  f32x4 aC = {0.f, 0.f, 0.f, 0.f};
  for (int kc = kc0; kc < kc1; ++kc) {
    const int kb = kc * 32 + l4 * 8;             // per-lane k base
    // B-frag: 8 consecutive fp32 from the x-row (32B contiguous)
    const float4 v0 = *reinterpret_cast<const float4*>(xs + kb);
    const float4 v1 = *reinterpret_cast<const float4*>(xs + kb + 4);
    bf16x8 xh, xl;
    {
      BfPair p;
      p = splitbf(v0.x); xh[0] = p.hi; xl[0] = p.lo;
      p = splitbf(v0.y); xh[1] = p.hi; xl[1] = p.lo;
      p = splitbf(v0.z); xh[2] = p.hi; xl[2] = p.lo;
      p = splitbf(v0.w); xh[3] = p.hi; xl[3] = p.lo;
      p = splitbf(v1.x); xh[4] = p.hi; xl[4] = p.lo;
      p = splitbf(v1.y); xh[5] = p.hi; xl[5] = p.lo;
      p = splitbf(v1.z); xh[6] = p.hi; xl[6] = p.lo;
      p = splitbf(v1.w); xh[7] = p.hi; xl[7] = p.lo;
    }
    // A-frag: 8 strided fp32 from W1[k][h] (lanes 0..15 share cachelines)
    bf16x8 wh, wl;
#pragma unroll
    for (int j = 0; j < 8; ++j) {
      const BfPair p = splitbf(W1[(size_t)(kb + j) * H1D + hrow]);
      wh[j] = p.hi; wl[j] = p.lo;
    }
    aA = __builtin_amdgcn_mfma_f32_16x16x32_bf16(wh, xh, aA, 0, 0, 0);
    aB = __builtin_amdgcn_mfma_f32_16x16x32_bf16(wl, xh, aB, 0, 0, 0);
    aC = __builtin_amdgcn_mfma_f32_16x16x32_bf16(wh, xl, aC, 0, 0, 0);
  }
#pragma unroll
  for (int r = 0; r < 4; ++r) {                  // C: row(h)=l4*4+r, col=l15
    const int h = mt * 16 + l4 * 4 + r;
    PTp[((size_t)q * H1D + h) * NTOT + nc * 16 + l15] = aA[r] + aB[r] + aC[r];
  }
}

// ---------------- K2: pair tiles via MFMA (validated body) ----------------
__global__ __launch_bounds__(256) void pair_kernel(
    const float* __restrict__ PTp, const float* __restrict__ b1,
    const float* __restrict__ W2, const float* __restrict__ b2,
    const float* __restrict__ W3, const float* __restrict__ b3,
    float* __restrict__ out) {
  __shared__ float sX[16][68];   // 272B row stride -> b128 conflict-free
  __shared__ float sY[16][68];
  __shared__ float sO[16][16];

  const int tid = threadIdx.x;
  const int wave = tid >> 6, lane = tid & 63;
  const int l15 = lane & 15, l4 = lane >> 4;
  const int wb = blockIdx.x * 16, qb = blockIdx.y * 16;

  {  // stage: sX[r][h] = sum_q PTp[q][h][wb+r] + b1[h]; sY same from y cols
    const int h = tid >> 2, r0 = (tid & 3) << 2;
    f32x4 sx = {0.f, 0.f, 0.f, 0.f}, sy = {0.f, 0.f, 0.f, 0.f};
#pragma unroll
    for (int q = 0; q < KQ; ++q) {
      sx += *reinterpret_cast<const f32x4*>(&PTp[((size_t)q * H1D + h) * NTOT + wb + r0]);
      sy += *reinterpret_cast<const f32x4*>(&PTp[((size_t)q * H1D + h) * NTOT + NROW + qb + r0]);
    }
    const float b1h = b1[h];
#pragma unroll
    for (int i = 0; i < 4; ++i) {   // 2-way bank aliasing only (free)
      sX[r0 + i][h] = sx[i] + b1h;
      sY[r0 + i][h] = sy[i];
    }
  }

  // B fragments (W2) direct from global (8KB, L1/L2-hot)
  bf16x8 bfr[2][2];
#pragma unroll
  for (int nt = 0; nt < 2; ++nt)
#pragma unroll
    for (int ks = 0; ks < 2; ++ks)
#pragma unroll
      for (int j = 0; j < 8; ++j)
        bfr[nt][ks][j] = (short)f2bf_u(W2[(ks * 32 + l4 * 8 + j) * H2D + nt * 16 + l15]);
  const float b2v0 = b2[l15], b2v1 = b2[16 + l15];
  const float w3v0 = W3[l15], w3v1 = W3[16 + l15];
  const float b3v = b3[0];

  f32x4 acc[4][2];
#pragma unroll
  for (int mt = 0; mt < 4; ++mt)
#pragma unroll
    for (int r = 0; r < 4; ++r) { acc[mt][0][r] = b2v0; acc[mt][1][r] = b2v1; }

  __syncthreads();

  // A fragments: row = l15 (y idx), k = ks*32 + l4*8 + j ; value = relu(Px-Py)
#pragma unroll
  for (int ks = 0; ks < 2; ++ks) {
    const int kb = ks * 32 + l4 * 8;
    const float4 y0 = *reinterpret_cast<const float4*>(&sY[l15][kb]);
    const float4 y1 = *reinterpret_cast<const float4*>(&sY[l15][kb + 4]);
#pragma unroll
    for (int mt = 0; mt < 4; ++mt) {
      const int lw = wave * 4 + mt;
      const float4 x0 = *reinterpret_cast<const float4*>(&sX[lw][kb]);
      const float4 x1 = *reinterpret_cast<const float4*>(&sX[lw][kb + 4]);
      bf16x8 af; float v;
      v = x0.x - y0.x; af[0] = (short)f2bf_u(v > 0.f ? v : 0.f);
      v = x0.y - y0.y; af[1] = (short)f2bf_u(v > 0.f ? v : 0.f);
      v = x0.z - y0.z; af[2] = (short)f2bf_u(v > 0.f ? v : 0.f);
      v = x0.w - y0.w; af[3] = (short)f2bf_u(v > 0.f ? v : 0.f);
      v = x1.x - y1.x; af[4] = (short)f2bf_u(v > 0.f ? v : 0.f);
      v = x1.y - y1.y; af[5] = (short)f2bf_u(v > 0.f ? v : 0.f);
      v = x1.z - y1.z; af[6] = (short)f2bf_u(v > 0.f ? v : 0.f);
      v = x1.w - y1.w; af[7] = (short)f2bf_u(v > 0.f ? v : 0.f);
      acc[mt][0] = __builtin_amdgcn_mfma_f32_16x16x32_bf16(af, bfr[0][ks], acc[mt][0], 0, 0, 0);
      acc[mt][1] = __builtin_amdgcn_mfma_f32_16x16x32_bf16(af, bfr[1][ks], acc[mt][1], 0, 0, 0);
    }
  }

  // layer 3: o = relu(sum_n relu(h2[n]) * W3[n] + b3), reduce 16 n-lanes
#pragma unroll
  for (int mt = 0; mt < 4; ++mt) {
    float t[4];
#pragma unroll
    for (int r = 0; r < 4; ++r) {
      const float q0 = acc[mt][0][r] > 0.f ? acc[mt][0][r] : 0.f;
      const float q1 = acc[mt][1][r] > 0.f ? acc[mt][1][r] : 0.f;
      t[r] = fmaf(q0, w3v0, q1 * w3v1);
    }
#pragma unroll
    for (int off = 1; off < 16; off <<= 1) {
#pragma unroll
      for (int r = 0; r < 4; ++r) t[r] += __shfl_xor(t[r], off, 64);
    }
    if (l15 == 0) {
#pragma unroll
      for (int r = 0; r < 4; ++r) {
        const float o = t[r] + b3v;
        sO[wave * 4 + mt][l4 * 4 + r] = o > 0.f ? o : 0.f;   // [lw][lq]
      }
    }
  }
  __syncthreads();
  out[(size_t)(wb + (tid >> 4)) * NROW + qb + (tid & 15)] = sO[tid >> 4][tid & 15];
}

extern "C" void kernel_launch(void* const* d_in, const int* in_sizes, int n_in,
                              void* d_out, int out_size, void* d_ws, size_t ws_size,
                              hipStream_t stream) {
  const float* x  = (const float*)d_in[0];
  const float* y  = (const float*)d_in[1];
  const float* W1 = (const float*)d_in[2];
  const float* b1 = (const float*)d_in[3];
  const float* W2 = (const float*)d_in[4];
  const float* b2 = (const float*)d_in[5];
  const float* W3 = (const float*)d_in[6];
  const float* b3 = (const float*)d_in[7];
  float* out = (float*)d_out;

  float* PTp = (float*)d_ws;   // KQ*64*1024*4 = 2 MB

  proj_kernel<<<512, 256, 0, stream>>>(x, y, W1, PTp);   // 64 nc x 8 q
  pair_kernel<<<dim3(32, 32), 256, 0, stream>>>(PTp, b1, W2, b2, W3, b3, out);
}